// Round 1
// baseline (408.859 us; speedup 1.0000x reference)
//
#include <hip/hip_runtime.h>
#include <math.h>

#define DDIM 256
#define NWAVES 4

// Kernel A: offsets[i] = lower_bound(seg, i) for i in [0, S]; seg is sorted.
__global__ void seg_offsets_kernel(const int* __restrict__ seg, int E, int S,
                                   int* __restrict__ offs) {
    int i = blockIdx.x * blockDim.x + threadIdx.x;
    if (i > S) return;
    int lo = 0, hi = E;
    while (lo < hi) {
        int mid = (lo + hi) >> 1;
        if (seg[mid] < i) lo = mid + 1; else hi = mid;
    }
    offs[i] = lo;
}

// Kernel B: one block (4 waves) per segment. Each wave does online softmax
// over its strided subset of edges, holding each gathered z-row entirely in
// registers (lane l holds dims [4l,4l+4) as float4). Merge waves via LDS.
__global__ __launch_bounds__(256)
void segpool_kernel(const float* __restrict__ z,
                    const float* __restrict__ attn_w,
                    const float* __restrict__ attn_b,
                    const int* __restrict__ idx,
                    const int* __restrict__ offs,
                    float* __restrict__ out) {
    const int s     = blockIdx.x;
    const int start = offs[s];
    const int end   = offs[s + 1];
    const int tid   = threadIdx.x;

    if (end <= start) {                 // empty segment -> zeros (d_out is poisoned)
        out[(long)s * DDIM + tid] = 0.0f;
        return;
    }

    const int wave = tid >> 6;
    const int lane = tid & 63;
    const float4 wv = ((const float4*)attn_w)[lane];  // this lane's 4 weight dims
    const float  b  = attn_b[0];
    const float4* __restrict__ z4 = (const float4*)z;

    float  m = -INFINITY;
    float  l = 0.0f;
    float4 acc = make_float4(0.f, 0.f, 0.f, 0.f);

    for (int e = start + wave; e < end; e += NWAVES) {
        const int   row = idx[e];
        const float4 v  = z4[(long)row * (DDIM / 4) + lane];
        float part = v.x * wv.x + v.y * wv.y + v.z * wv.z + v.w * wv.w;
        #pragma unroll
        for (int sh = 32; sh >= 1; sh >>= 1)
            part += __shfl_xor(part, sh);             // all 64 lanes get the dot
        const float logit = part + b;

        const float nm    = fmaxf(m, logit);
        const float alpha = __expf(m - nm);           // 0 when m was -inf
        const float p     = __expf(logit - nm);
        l      = l * alpha + p;
        acc.x  = acc.x * alpha + p * v.x;
        acc.y  = acc.y * alpha + p * v.y;
        acc.z  = acc.z * alpha + p * v.z;
        acc.w  = acc.w * alpha + p * v.w;
        m      = nm;
    }

    // Merge the 4 waves' (m, l, acc) via LDS.
    __shared__ float lds_m[NWAVES];
    __shared__ float lds_l[NWAVES];
    __shared__ float lds_acc[NWAVES][DDIM];
    if (lane == 0) { lds_m[wave] = m; lds_l[wave] = l; }
    __syncthreads();

    const float M = fmaxf(fmaxf(lds_m[0], lds_m[1]), fmaxf(lds_m[2], lds_m[3]));
    float den = 0.0f;
    #pragma unroll
    for (int w = 0; w < NWAVES; ++w)
        den += __expf(lds_m[w] - M) * lds_l[w];       // -inf waves contribute 0

    const float scale = __expf(m - M);                // wave-uniform
    lds_acc[wave][4 * lane + 0] = acc.x * scale;
    lds_acc[wave][4 * lane + 1] = acc.y * scale;
    lds_acc[wave][4 * lane + 2] = acc.z * scale;
    lds_acc[wave][4 * lane + 3] = acc.w * scale;
    __syncthreads();

    const float o = lds_acc[0][tid] + lds_acc[1][tid] +
                    lds_acc[2][tid] + lds_acc[3][tid];
    out[(long)s * DDIM + tid] = o / den;
}

extern "C" void kernel_launch(void* const* d_in, const int* in_sizes, int n_in,
                              void* d_out, int out_size, void* d_ws, size_t ws_size,
                              hipStream_t stream) {
    const float* z      = (const float*)d_in[0];
    const float* attn_w = (const float*)d_in[1];
    const float* attn_b = (const float*)d_in[2];
    const int*   idx    = (const int*)d_in[3];
    const int*   seg    = (const int*)d_in[4];
    float*       out    = (float*)d_out;

    const int E = in_sizes[3];
    const int S = out_size / DDIM;
    int* offs = (int*)d_ws;                  // (S+1) ints of scratch

    const int threads = 256;
    const int gridA = (S + 1 + threads - 1) / threads;
    seg_offsets_kernel<<<gridA, threads, 0, stream>>>(seg, E, S, offs);
    segpool_kernel<<<S, threads, 0, stream>>>(z, attn_w, attn_b, idx, offs, out);
}